// Round 3
// baseline (338.727 us; speedup 1.0000x reference)
//
#include <hip/hip_runtime.h>
#include <math.h>

#define BB 64
#define TT 1024
#define CC 64
#define HH 32
#define KNN 10
#define BIGF 3.0e38f

typedef float v2f __attribute__((ext_vector_type(2)));
typedef float v4f __attribute__((ext_vector_type(4)));

__device__ __forceinline__ v2f pk_fma(v2f a, v2f b, v2f c) {
    v2f d;
    asm("v_pk_fma_f32 %0, %1, %2, %3" : "=v"(d) : "v"(a), "v"(b), "v"(c));
    return d;
}
__device__ __forceinline__ v2f pk_add(v2f a, v2f b) {
    v2f d;
    asm("v_pk_add_f32 %0, %1, %2" : "=v"(d) : "v"(a), "v"(b));
    return d;
}

// ---------------- Kernel A: h = x@W1 + b1, hsq[row] = 0.5*|h_row|^2 ------------
__global__ __launch_bounds__(256) void h_kernel(
    const float* __restrict__ x, const float* __restrict__ W1,
    const float* __restrict__ b1, float* __restrict__ h, float* __restrict__ hsq)
{
    __shared__ float w1s[CC][HH];
    __shared__ float b1s[HH];
    int tid = threadIdx.x;
    for (int i = tid; i < CC * HH; i += 256) w1s[i >> 5][i & 31] = W1[i];
    if (tid < HH) b1s[tid] = b1[tid];
    __syncthreads();

    int row = blockIdx.x * 256 + tid;           // 0 .. B*T-1
    const float4* xr = (const float4*)(x + (size_t)row * CC);
    float acc[HH];
    #pragma unroll
    for (int j = 0; j < HH; ++j) acc[j] = b1s[j];
    #pragma unroll
    for (int c4 = 0; c4 < CC / 4; ++c4) {
        float4 xv = xr[c4];
        #pragma unroll
        for (int j = 0; j < HH; ++j) {
            acc[j] = fmaf(xv.x, w1s[c4 * 4 + 0][j], acc[j]);
            acc[j] = fmaf(xv.y, w1s[c4 * 4 + 1][j], acc[j]);
            acc[j] = fmaf(xv.z, w1s[c4 * 4 + 2][j], acc[j]);
            acc[j] = fmaf(xv.w, w1s[c4 * 4 + 3][j], acc[j]);
        }
    }
    float s = 0.f;
    #pragma unroll
    for (int j = 0; j < HH; ++j) s = fmaf(acc[j], acc[j], s);
    float* hr = h + (size_t)row * HH;
    #pragma unroll
    for (int q = 0; q < HH / 4; ++q) {
        float4 v = { acc[4*q], acc[4*q+1], acc[4*q+2], acc[4*q+3] };
        ((float4*)hr)[q] = v;
    }
    hsq[row] = 0.5f * s;
}

// ------------- Kernel B: kNN + laplace smooth + tanh + W2 GEMM ---------------
// grid = B * (T/64) blocks, 256 threads (4 waves).
// Each wave: 64 rows (1 per lane). 4 waves split the s-range 4-ways.
// launch_bounds(256,3): ~170 VGPR cap so full-row prefetch slots fit in VGPRs
// (forced-VMEM path). LDS 33KB caps blocks/CU at 4 anyway.
__global__ __launch_bounds__(256, 3) void lap_kernel(
    const float* __restrict__ h, const float* __restrict__ hsq,
    const float* __restrict__ W2, const float* __restrict__ b2,
    float* __restrict__ out)
{
    __shared__ float s_key[4][64][KNN];
    __shared__ int   s_idx[4][64][KNN];
    __shared__ float a_lds[64][HH + 1];
    __shared__ float w2s[HH][HH];
    __shared__ float b2s[HH];

    int tid  = threadIdx.x;
    int lane = tid & 63;
    int wid  = __builtin_amdgcn_readfirstlane(tid >> 6);

    int bb = blockIdx.x >> 4;            // batch index (16 row-blocks / batch)
    int rb = (blockIdx.x & 15) << 6;     // row base within batch
    int row = rb + lane;

    for (int i = tid; i < HH * HH; i += 256) w2s[i >> 5][i & 31] = W2[i];
    if (tid < HH) b2s[tid] = b2[tid];

    const float* hb  = h   + (size_t)bb * TT * HH;
    const float* sqb = hsq + (size_t)bb * TT;

    // opaque zero VGPR: forces candidate loads to VMEM (in-order vmcnt)
    // instead of SMEM (out-of-order lgkmcnt -> conservative waits).
    int vz;
    asm("v_mov_b32 %0, 0" : "=v"(vz));

    // own row, negated, as 16 float2 for v_pk_fma_f32
    v2f hn[16];
    {
        const v4f* hrp = (const v4f*)(hb + (size_t)row * HH);
        #pragma unroll
        for (int q = 0; q < 8; ++q) {
            v4f v = hrp[q];
            hn[2*q]   = (v2f){ -v[0], -v[1] };
            hn[2*q+1] = (v2f){ -v[2], -v[3] };
        }
    }

    float bd[KNN]; int bi[KNN];
    #pragma unroll
    for (int j = 0; j < KNN; ++j) { bd[j] = BIGF; bi[j] = -1; }

    int s0 = wid * (TT / 4);

    // full-row prefetch slot (forced VMEM via vz)
    v4f c0, c1, c2, c3, c4, c5, c6, c7; float chs;
    {
        const v4f* p = (const v4f*)(hb + (size_t)s0 * HH);
        c0 = p[vz+0]; c1 = p[vz+1]; c2 = p[vz+2]; c3 = p[vz+3];
        c4 = p[vz+4]; c5 = p[vz+5]; c6 = p[vz+6]; c7 = p[vz+7];
        chs = sqb[s0 + vz];
    }

    #pragma unroll 2
    for (int i = 0; i < TT / 4; ++i) {
        int s  = s0 + i;                             // wave-uniform
        int sn = s0 + ((i + 1) & (TT / 4 - 1));      // wrap: harmless reload
        // issue next-row loads (stay outstanding across this body: vmcnt(N))
        const v4f* p = (const v4f*)(hb + (size_t)sn * HH);
        v4f n0 = p[vz+0], n1 = p[vz+1], n2 = p[vz+2], n3 = p[vz+3];
        v4f n4 = p[vz+4], n5 = p[vz+5], n6 = p[vz+6], n7 = p[vz+7];
        float nhs = sqb[sn + vz];

        // key = 0.5*sq_s - dot(h_t, h_s)  (== 0.5*(d2 - sq_t), order-equal)
        v2f accA = (v2f){ chs, 0.f };
        v2f accB = (v2f){ 0.f, 0.f };
        accA = pk_fma(hn[0],  (v2f){c0[0], c0[1]}, accA);
        accB = pk_fma(hn[1],  (v2f){c0[2], c0[3]}, accB);
        accA = pk_fma(hn[2],  (v2f){c1[0], c1[1]}, accA);
        accB = pk_fma(hn[3],  (v2f){c1[2], c1[3]}, accB);
        accA = pk_fma(hn[4],  (v2f){c2[0], c2[1]}, accA);
        accB = pk_fma(hn[5],  (v2f){c2[2], c2[3]}, accB);
        accA = pk_fma(hn[6],  (v2f){c3[0], c3[1]}, accA);
        accB = pk_fma(hn[7],  (v2f){c3[2], c3[3]}, accB);
        accA = pk_fma(hn[8],  (v2f){c4[0], c4[1]}, accA);
        accB = pk_fma(hn[9],  (v2f){c4[2], c4[3]}, accB);
        accA = pk_fma(hn[10], (v2f){c5[0], c5[1]}, accA);
        accB = pk_fma(hn[11], (v2f){c5[2], c5[3]}, accB);
        accA = pk_fma(hn[12], (v2f){c6[0], c6[1]}, accA);
        accB = pk_fma(hn[13], (v2f){c6[2], c6[3]}, accB);
        accA = pk_fma(hn[14], (v2f){c7[0], c7[1]}, accA);
        accB = pk_fma(hn[15], (v2f){c7[2], c7[3]}, accB);
        v2f accs = pk_add(accA, accB);
        float key = accs[0] + accs[1];
        key = (s == row) ? BIGF : key;               // exclude self

        // sorted insert: all compares vs OLD bd, then shifted selects
        bool m[KNN];
        #pragma unroll
        for (int j = 0; j < KNN; ++j) m[j] = key < bd[j];
        #pragma unroll
        for (int j = KNN - 1; j >= 1; --j) {
            bd[j] = m[j] ? (m[j-1] ? bd[j-1] : key) : bd[j];
            bi[j] = m[j] ? (m[j-1] ? bi[j-1] : s  ) : bi[j];
        }
        bd[0] = m[0] ? key : bd[0];
        bi[0] = m[0] ? s   : bi[0];

        c0 = n0; c1 = n1; c2 = n2; c3 = n3;
        c4 = n4; c5 = n5; c6 = n6; c7 = n7;
        chs = nhs;
    }

    __syncthreads();   // all waves done with main loop before s_key reuse
    #pragma unroll
    for (int j = 0; j < KNN; ++j) {
        s_key[wid][lane][j] = bd[j];
        s_idx[wid][lane][j] = bi[j];
    }
    __syncthreads();

    if (wid == 0) {
        // merge the 4 sorted lists (chunk order == ascending s => stable ties)
        int p0_ = 0, p1_ = 0, p2_ = 0, p3_ = 0;
        float h0 = s_key[0][lane][0], h1 = s_key[1][lane][0];
        float h2 = s_key[2][lane][0], h3 = s_key[3][lane][0];
        int idxs[KNN];
        #pragma unroll
        for (int j = 0; j < KNN; ++j) {
            int c = 0; float m = h0;
            if (h1 < m) { m = h1; c = 1; }
            if (h2 < m) { m = h2; c = 2; }
            if (h3 < m) { m = h3; c = 3; }
            if (c == 0)      { idxs[j] = s_idx[0][lane][p0_]; ++p0_; h0 = (p0_ < KNN) ? s_key[0][lane][p0_] : BIGF; }
            else if (c == 1) { idxs[j] = s_idx[1][lane][p1_]; ++p1_; h1 = (p1_ < KNN) ? s_key[1][lane][p1_] : BIGF; }
            else if (c == 2) { idxs[j] = s_idx[2][lane][p2_]; ++p2_; h2 = (p2_ < KNN) ? s_key[2][lane][p2_] : BIGF; }
            else             { idxs[j] = s_idx[3][lane][p3_]; ++p3_; h3 = (p3_ < KNN) ? s_key[3][lane][p3_] : BIGF; }
        }

        // exact weights + smooth (matches reference's gathered-diff path)
        float sm[HH];
        #pragma unroll
        for (int j = 0; j < HH; ++j) sm[j] = 0.f;
        float wsum = 0.f;
        #pragma unroll 2
        for (int k = 0; k < KNN; ++k) {
            const float4* np_ = (const float4*)(hb + (size_t)idxs[k] * HH);
            float nb[HH];
            #pragma unroll
            for (int q = 0; q < HH / 4; ++q) {
                float4 v = np_[q];
                nb[q*4+0] = v.x; nb[q*4+1] = v.y; nb[q*4+2] = v.z; nb[q*4+3] = v.w;
            }
            float d2 = 0.f;
            #pragma unroll
            for (int q = 0; q < 16; ++q) {
                float df0 = nb[2*q]   + hn[q][0];   // nb - h_t
                float df1 = nb[2*q+1] + hn[q][1];
                d2 = fmaf(df0, df0, d2);
                d2 = fmaf(df1, df1, d2);
            }
            float wk = expf(-0.5f * d2);
            wsum += wk;
            #pragma unroll
            for (int j = 0; j < HH; ++j) sm[j] = fmaf(wk, nb[j], sm[j]);
        }
        float inv = 1.0f / (wsum + 1e-8f);
        #pragma unroll
        for (int j = 0; j < HH; ++j) {
            // lap = h_t - smooth = -(hn + smooth)   (hn = -h_t)
            float lap = -fmaf(sm[j], inv, hn[j >> 1][j & 1]);
            a_lds[lane][j] = tanhf(lap);
        }
    }
    __syncthreads();

    // out = a @ W2 + b2 ; thread -> (row r, 8 consecutive output dims)
    int r   = tid >> 2;
    int c0_ = (tid & 3) << 3;
    float o[8];
    #pragma unroll
    for (int u = 0; u < 8; ++u) o[u] = b2s[c0_ + u];
    #pragma unroll
    for (int j = 0; j < HH; ++j) {
        float av = a_lds[r][j];
        #pragma unroll
        for (int u = 0; u < 8; ++u) o[u] = fmaf(av, w2s[j][c0_ + u], o[u]);
    }
    float* op = out + ((size_t)bb * TT + rb + r) * HH + c0_;
    float4 o1 = { o[0], o[1], o[2], o[3] };
    float4 o2 = { o[4], o[5], o[6], o[7] };
    ((float4*)op)[0] = o1;
    ((float4*)op)[1] = o2;
}

extern "C" void kernel_launch(void* const* d_in, const int* in_sizes, int n_in,
                              void* d_out, int out_size, void* d_ws, size_t ws_size,
                              hipStream_t stream) {
    const float* x  = (const float*)d_in[0];
    const float* W1 = (const float*)d_in[1];
    const float* b1 = (const float*)d_in[2];
    const float* W2 = (const float*)d_in[3];
    const float* b2 = (const float*)d_in[4];
    float* outp = (float*)d_out;

    // workspace layout: h (B*T*H floats) | hsq (B*T floats)  ~= 8.65 MB
    float* h   = (float*)d_ws;
    float* hsq = h + (size_t)BB * TT * HH;

    h_kernel<<<(BB * TT) / 256, 256, 0, stream>>>(x, W1, b1, h, hsq);
    lap_kernel<<<BB * (TT / 64), 256, 0, stream>>>(h, hsq, W2, b2, outp);
}

// Round 4
// 180.494 us; speedup vs baseline: 1.8767x; 1.8767x over previous
//
#include <hip/hip_runtime.h>
#include <math.h>

#define BB 64
#define TT 1024
#define CC 64
#define HH 32
#define KNN 10
#define SPLIT 8
#define CHUNK (TT / SPLIT)   // 128
#define BIGF 3.0e38f

typedef float v2f __attribute__((ext_vector_type(2)));
typedef float v4f __attribute__((ext_vector_type(4)));

// VOP3P packed fp32 ops; row operand lives in an SGPR pair ("s" constraint,
// legal: one scalar read per vector instr). hn/acc in VGPRs.
__device__ __forceinline__ v2f pk_fma_vs(v2f a_v, v2f b_s, v2f c_v) {
    v2f d;
    asm("v_pk_fma_f32 %0, %1, %2, %3" : "=v"(d) : "v"(a_v), "s"(b_s), "v"(c_v));
    return d;
}
__device__ __forceinline__ v2f pk_mul_vs(v2f a_v, v2f b_s) {
    v2f d;
    asm("v_pk_mul_f32 %0, %1, %2" : "=v"(d) : "v"(a_v), "s"(b_s));
    return d;
}
__device__ __forceinline__ v2f pk_add_vv(v2f a, v2f b) {
    v2f d;
    asm("v_pk_add_f32 %0, %1, %2" : "=v"(d) : "v"(a), "v"(b));
    return d;
}

// ---------------- Kernel A: h = x@W1 + b1, hsq[row] = 0.5*|h_row|^2 ----------
__global__ __launch_bounds__(256) void h_kernel(
    const float* __restrict__ x, const float* __restrict__ W1,
    const float* __restrict__ b1, float* __restrict__ h, float* __restrict__ hsq)
{
    __shared__ float w1s[CC][HH];
    __shared__ float b1s[HH];
    int tid = threadIdx.x;
    for (int i = tid; i < CC * HH; i += 256) w1s[i >> 5][i & 31] = W1[i];
    if (tid < HH) b1s[tid] = b1[tid];
    __syncthreads();

    int row = blockIdx.x * 256 + tid;
    const float4* xr = (const float4*)(x + (size_t)row * CC);
    float acc[HH];
    #pragma unroll
    for (int j = 0; j < HH; ++j) acc[j] = b1s[j];
    #pragma unroll
    for (int c4 = 0; c4 < CC / 4; ++c4) {
        float4 xv = xr[c4];
        #pragma unroll
        for (int j = 0; j < HH; ++j) {
            acc[j] = fmaf(xv.x, w1s[c4 * 4 + 0][j], acc[j]);
            acc[j] = fmaf(xv.y, w1s[c4 * 4 + 1][j], acc[j]);
            acc[j] = fmaf(xv.z, w1s[c4 * 4 + 2][j], acc[j]);
            acc[j] = fmaf(xv.w, w1s[c4 * 4 + 3][j], acc[j]);
        }
    }
    float s = 0.f;
    #pragma unroll
    for (int j = 0; j < HH; ++j) s = fmaf(acc[j], acc[j], s);
    float* hr = h + (size_t)row * HH;
    #pragma unroll
    for (int q = 0; q < HH / 4; ++q) {
        float4 v = { acc[4*q], acc[4*q+1], acc[4*q+2], acc[4*q+3] };
        ((float4*)hr)[q] = v;
    }
    hsq[row] = 0.5f * s;
}

// ------------- Kernel B: kNN + laplace smooth + tanh + W2 GEMM ---------------
// 512 threads = 8 waves. Block owns 64 rows (1/lane); wave w handles candidate
// chunk [w*128, w*128+128) for all 64 rows (wave-uniform candidate -> SMEM).
// grid = 1024 blocks -> 8192 waves = 8/SIMD target occupancy.
__global__ __launch_bounds__(512, 4) void lap_kernel(
    const float* __restrict__ h, const float* __restrict__ hsq,
    const float* __restrict__ W2, const float* __restrict__ b2,
    float* __restrict__ out)
{
    __shared__ float s_key[SPLIT][64][KNN];            // 20.5 KB (reused as a_lds)
    __shared__ unsigned short s_idx[SPLIT][64][KNN];   // 10 KB
    __shared__ float w2s[HH][HH];
    __shared__ float b2s[HH];

    int tid  = threadIdx.x;
    int lane = tid & 63;
    int wid  = __builtin_amdgcn_readfirstlane(tid >> 6);   // chunk id 0..7

    int bb  = blockIdx.x >> 4;           // batch
    int rb  = (blockIdx.x & 15) << 6;    // row base within batch
    int row = rb + lane;                 // in-batch row, one per lane

    for (int i = tid; i < HH * HH; i += 512) w2s[i >> 5][i & 31] = W2[i];
    if (tid < HH) b2s[tid] = b2[tid];

    const float* hb  = h   + (size_t)bb * TT * HH;
    const float* sqb = hsq + (size_t)bb * TT;

    // own row, negated, 16 x float2 (VGPRs; per-lane VMEM loads)
    v2f hn[16];
    {
        const v4f* hrp = (const v4f*)(hb + (size_t)row * HH);
        #pragma unroll
        for (int q = 0; q < 8; ++q) {
            v4f v = hrp[q];
            hn[2*q]   = (v2f){ -v[0], -v[1] };
            hn[2*q+1] = (v2f){ -v[2], -v[3] };
        }
    }

    int s0 = wid * CHUNK;
    int self_i = row - s0;                       // iteration at which s == row
    if ((unsigned)self_i >= (unsigned)CHUNK) self_i = -1;

    float bd[KNN]; int bi[KNN];
    #pragma unroll
    for (int j = 0; j < KNN; ++j) { bd[j] = BIGF; bi[j] = 0; }

    // prefetch row 0 of this chunk into SGPRs (wave-uniform address -> s_load)
    v2f cr[16]; float chs;
    {
        const v2f* p = (const v2f*)(hb + (size_t)s0 * HH);
        #pragma unroll
        for (int q = 0; q < 16; ++q) cr[q] = p[q];
        chs = sqb[s0];
    }

    #pragma unroll 2
    for (int i = 0; i < CHUNK; ++i) {
        int inext = (i + 1) & (CHUNK - 1);       // wrap: harmless reload
        const v2f* pn = (const v2f*)(hb + (size_t)(s0 + inext) * HH);
        v2f nr[16];
        #pragma unroll
        for (int q = 0; q < 16; ++q) nr[q] = pn[q];
        float nhs = sqb[s0 + inext];

        // key = 0.5*sq_s - dot(h_t, h_s)   (hn = -h_t)
        v2f accA = pk_mul_vs(hn[0], cr[0]);
        v2f accB = pk_mul_vs(hn[1], cr[1]);
        #pragma unroll
        for (int q = 2; q < 16; q += 2) {
            accA = pk_fma_vs(hn[q],     cr[q],     accA);
            accB = pk_fma_vs(hn[q + 1], cr[q + 1], accB);
        }
        v2f accS = pk_add_vv(accA, accB);
        float key = (accS[0] + accS[1]) + chs;
        key = (i == self_i) ? BIGF : key;        // exclude self (1 cmp + 1 sel)

        // branchless sorted top-10 insert; store i (SGPR) as the index
        bool m[KNN];
        #pragma unroll
        for (int j = 0; j < KNN; ++j) m[j] = key < bd[j];
        #pragma unroll
        for (int j = KNN - 1; j >= 1; --j) {
            bd[j] = m[j] ? (m[j-1] ? bd[j-1] : key) : bd[j];
            bi[j] = m[j] ? (m[j-1] ? bi[j-1] : i  ) : bi[j];
        }
        bd[0] = m[0] ? key : bd[0];
        bi[0] = m[0] ? i   : bi[0];

        #pragma unroll
        for (int q = 0; q < 16; ++q) cr[q] = nr[q];
        chs = nhs;
    }

    #pragma unroll
    for (int j = 0; j < KNN; ++j) {
        s_key[wid][lane][j] = bd[j];
        s_idx[wid][lane][j] = (unsigned short)(s0 + bi[j]);
    }
    __syncthreads();

    // a_lds aliases s_key (merge reads complete before writes, same wave)
    float* a_pool = &s_key[0][0][0];             // [64][33] layout, 8448 B

    if (wid == 0) {
        // 8-way merge of sorted 10-lists; strict < keeps lowest chunk on ties
        // (chunk order == ascending s => reference tie-break by lower index)
        float k0 = s_key[0][lane][0], k1 = s_key[1][lane][0];
        float k2 = s_key[2][lane][0], k3 = s_key[3][lane][0];
        float k4 = s_key[4][lane][0], k5 = s_key[5][lane][0];
        float k6 = s_key[6][lane][0], k7 = s_key[7][lane][0];
        int p0=0,p1=0,p2=0,p3=0,p4=0,p5=0,p6=0,p7=0;
        int idxs[KNN];
        #pragma unroll
        for (int j = 0; j < KNN; ++j) {
            float mn = k0; int c = 0;
            if (k1 < mn) { mn = k1; c = 1; }
            if (k2 < mn) { mn = k2; c = 2; }
            if (k3 < mn) { mn = k3; c = 3; }
            if (k4 < mn) { mn = k4; c = 4; }
            if (k5 < mn) { mn = k5; c = 5; }
            if (k6 < mn) { mn = k6; c = 6; }
            if (k7 < mn) { mn = k7; c = 7; }
            if      (c == 0) { idxs[j] = s_idx[0][lane][p0]; ++p0; k0 = (p0 < KNN) ? s_key[0][lane][p0] : BIGF; }
            else if (c == 1) { idxs[j] = s_idx[1][lane][p1]; ++p1; k1 = (p1 < KNN) ? s_key[1][lane][p1] : BIGF; }
            else if (c == 2) { idxs[j] = s_idx[2][lane][p2]; ++p2; k2 = (p2 < KNN) ? s_key[2][lane][p2] : BIGF; }
            else if (c == 3) { idxs[j] = s_idx[3][lane][p3]; ++p3; k3 = (p3 < KNN) ? s_key[3][lane][p3] : BIGF; }
            else if (c == 4) { idxs[j] = s_idx[4][lane][p4]; ++p4; k4 = (p4 < KNN) ? s_key[4][lane][p4] : BIGF; }
            else if (c == 5) { idxs[j] = s_idx[5][lane][p5]; ++p5; k5 = (p5 < KNN) ? s_key[5][lane][p5] : BIGF; }
            else if (c == 6) { idxs[j] = s_idx[6][lane][p6]; ++p6; k6 = (p6 < KNN) ? s_key[6][lane][p6] : BIGF; }
            else             { idxs[j] = s_idx[7][lane][p7]; ++p7; k7 = (p7 < KNN) ? s_key[7][lane][p7] : BIGF; }
        }

        // exact weights + smooth (matches reference's gathered-diff path)
        float sm[HH];
        #pragma unroll
        for (int j = 0; j < HH; ++j) sm[j] = 0.f;
        float wsum = 0.f;
        #pragma unroll 2
        for (int k = 0; k < KNN; ++k) {
            const v4f* np_ = (const v4f*)(hb + (size_t)idxs[k] * HH);
            float nb[HH];
            #pragma unroll
            for (int q = 0; q < HH / 4; ++q) {
                v4f v = np_[q];
                nb[q*4+0] = v[0]; nb[q*4+1] = v[1]; nb[q*4+2] = v[2]; nb[q*4+3] = v[3];
            }
            float d2 = 0.f;
            #pragma unroll
            for (int q = 0; q < 16; ++q) {
                float df0 = nb[2*q]   + hn[q][0];   // nb - h_t
                float df1 = nb[2*q+1] + hn[q][1];
                d2 = fmaf(df0, df0, d2);
                d2 = fmaf(df1, df1, d2);
            }
            float wk = expf(-0.5f * d2);
            wsum += wk;
            #pragma unroll
            for (int j = 0; j < HH; ++j) sm[j] = fmaf(wk, nb[j], sm[j]);
        }
        float inv = 1.0f / (wsum + 1e-8f);
        #pragma unroll
        for (int j = 0; j < HH; ++j) {
            float lap = -fmaf(sm[j], inv, hn[j >> 1][j & 1]);  // h_t - smooth
            a_pool[lane * 33 + j] = tanhf(lap);
        }
    }
    __syncthreads();

    // out = a @ W2 + b2 ; 512 threads -> (row r, 4 consecutive output dims)
    int r   = tid >> 3;            // 0..63
    int c0_ = (tid & 7) << 2;      // 0,4,...,28
    float o[4];
    #pragma unroll
    for (int u = 0; u < 4; ++u) o[u] = b2s[c0_ + u];
    #pragma unroll
    for (int j = 0; j < HH; ++j) {
        float av = a_pool[r * 33 + j];
        #pragma unroll
        for (int u = 0; u < 4; ++u) o[u] = fmaf(av, w2s[j][c0_ + u], o[u]);
    }
    float* op = out + ((size_t)bb * TT + rb + r) * HH + c0_;
    float4 o1 = { o[0], o[1], o[2], o[3] };
    *((float4*)op) = o1;
}

extern "C" void kernel_launch(void* const* d_in, const int* in_sizes, int n_in,
                              void* d_out, int out_size, void* d_ws, size_t ws_size,
                              hipStream_t stream) {
    const float* x  = (const float*)d_in[0];
    const float* W1 = (const float*)d_in[1];
    const float* b1 = (const float*)d_in[2];
    const float* W2 = (const float*)d_in[3];
    const float* b2 = (const float*)d_in[4];
    float* outp = (float*)d_out;

    float* h   = (float*)d_ws;
    float* hsq = h + (size_t)BB * TT * HH;

    h_kernel<<<(BB * TT) / 256, 256, 0, stream>>>(x, W1, b1, h, hsq);
    lap_kernel<<<BB * (TT / 64), 512, 0, stream>>>(h, hsq, W2, b2, outp);
}

// Round 9
// 163.173 us; speedup vs baseline: 2.0759x; 1.1062x over previous
//
#include <hip/hip_runtime.h>
#include <math.h>

#define BB 64
#define TT 1024
#define CC 64
#define HH 32
#define KNN 10
#define SPLIT 8
#define CHUNK (TT / SPLIT)   // 128
#define BIGF 3.0e38f

typedef float v2f __attribute__((ext_vector_type(2)));
typedef float v4f __attribute__((ext_vector_type(4)));

__device__ __forceinline__ v2f pk_fma_vs(v2f a_v, v2f b_s, v2f c_v) {
    v2f d;
    asm("v_pk_fma_f32 %0, %1, %2, %3" : "=v"(d) : "v"(a_v), "s"(b_s), "v"(c_v));
    return d;
}
__device__ __forceinline__ v2f pk_mul_vs(v2f a_v, v2f b_s) {
    v2f d;
    asm("v_pk_mul_f32 %0, %1, %2" : "=v"(d) : "v"(a_v), "s"(b_s));
    return d;
}
__device__ __forceinline__ v2f pk_add_vv(v2f a, v2f b) {
    v2f d;
    asm("v_pk_add_f32 %0, %1, %2" : "=v"(d) : "v"(a), "v"(b));
    return d;
}
__device__ __forceinline__ unsigned umn(unsigned a, unsigned b) { return a < b ? a : b; }
__device__ __forceinline__ unsigned umx(unsigned a, unsigned b) { return a > b ? a : b; }

// ---------------- Kernel A: h = x@W1 + b1, hsq[row] = 0.5*|h_row|^2 ----------
__global__ __launch_bounds__(256) void h_kernel(
    const float* __restrict__ x, const float* __restrict__ W1,
    const float* __restrict__ b1, float* __restrict__ h, float* __restrict__ hsq)
{
    __shared__ float w1s[CC][HH];
    __shared__ float b1s[HH];
    int tid = threadIdx.x;
    for (int i = tid; i < CC * HH; i += 256) w1s[i >> 5][i & 31] = W1[i];
    if (tid < HH) b1s[tid] = b1[tid];
    __syncthreads();

    int row = blockIdx.x * 256 + tid;
    const float4* xr = (const float4*)(x + (size_t)row * CC);
    float acc[HH];
    #pragma unroll
    for (int j = 0; j < HH; ++j) acc[j] = b1s[j];
    #pragma unroll
    for (int c4 = 0; c4 < CC / 4; ++c4) {
        float4 xv = xr[c4];
        #pragma unroll
        for (int j = 0; j < HH; ++j) {
            acc[j] = fmaf(xv.x, w1s[c4 * 4 + 0][j], acc[j]);
            acc[j] = fmaf(xv.y, w1s[c4 * 4 + 1][j], acc[j]);
            acc[j] = fmaf(xv.z, w1s[c4 * 4 + 2][j], acc[j]);
            acc[j] = fmaf(xv.w, w1s[c4 * 4 + 3][j], acc[j]);
        }
    }
    float s = 0.f;
    #pragma unroll
    for (int j = 0; j < HH; ++j) s = fmaf(acc[j], acc[j], s);
    float* hr = h + (size_t)row * HH;
    #pragma unroll
    for (int q = 0; q < HH / 4; ++q) {
        float4 v = { acc[4*q], acc[4*q+1], acc[4*q+2], acc[4*q+3] };
        ((float4*)hr)[q] = v;
    }
    hsq[row] = 0.5f * s;
}

// ------------- Kernel B: kNN + laplace smooth + tanh + W2 GEMM ---------------
// 512 threads = 8 waves; block owns 64 rows (1/lane); wave w scans candidate
// chunk [w*128, w*128+128) (wave-uniform -> SMEM broadcast).
// Keys: fixed-point u25 of (0.5*d2+1)*2^20 (granularity ~ fp32 ulp; clamp only
// hits keys that can't be top-10) with chunk-local index in low 7 bits.
// Top-10 kept with a 19-op min/max insert network.
__global__ __launch_bounds__(512, 4) void lap_kernel(
    const float* __restrict__ h, const float* __restrict__ hsq,
    const float* __restrict__ W2, const float* __restrict__ b2,
    float* __restrict__ out)
{
    __shared__ unsigned s_key[SPLIT][64][KNN];     // 20.5 KB (aliased as a_pool)
    __shared__ float w2s[HH][HH];
    __shared__ float b2s[HH];

    int tid  = threadIdx.x;
    int lane = tid & 63;
    int wid  = __builtin_amdgcn_readfirstlane(tid >> 6);   // chunk id 0..7

    int bb  = blockIdx.x >> 4;           // batch
    int rb  = (blockIdx.x & 15) << 6;    // row base within batch
    int row = rb + lane;

    for (int i = tid; i < HH * HH; i += 512) w2s[i >> 5][i & 31] = W2[i];
    if (tid < HH) b2s[tid] = b2[tid];

    const float* hb  = h   + (size_t)bb * TT * HH;
    const float* sqb = hsq + (size_t)bb * TT;

    // own row, negated (16 x float2, VGPRs)
    v2f hn[16];
    {
        const v4f* hrp = (const v4f*)(hb + (size_t)row * HH);
        #pragma unroll
        for (int q = 0; q < 8; ++q) {
            v4f v = hrp[q];
            hn[2*q]   = (v2f){ -v[0], -v[1] };
            hn[2*q+1] = (v2f){ -v[2], -v[3] };
        }
    }
    // per-lane bias: 0.5*sq_t + 1  (keeps key = 0.5*d2+1 >= 1, order-invariant)
    v2f cinit = (v2f){ sqb[row] + 1.0f, 0.0f };

    int s0 = wid * CHUNK;
    int self_i = row - s0;                      // chunk-local self position
    if ((unsigned)self_i >= (unsigned)CHUNK) self_i = -1;

    unsigned bd[KNN];
    #pragma unroll
    for (int j = 0; j < KNN; ++j) bd[j] = 0xFFFFFFFFu;

    // prefetch row 0 (wave-uniform -> s_load into SGPRs via "s" consumers)
    v2f cr[16]; float chs;
    {
        const v2f* p = (const v2f*)(hb + (size_t)s0 * HH);
        #pragma unroll
        for (int q = 0; q < 16; ++q) cr[q] = p[q];
        chs = sqb[s0];
    }

    #pragma unroll 2
    for (int i = 0; i < CHUNK; ++i) {
        int inext = (i + 1) & (CHUNK - 1);      // wrap: harmless reload
        const v2f* pn = (const v2f*)(hb + (size_t)(s0 + inext) * HH);
        v2f nr[16];
        #pragma unroll
        for (int q = 0; q < 16; ++q) nr[q] = pn[q];
        float nhs = sqb[s0 + inext];

        // keyf = (0.5*sq_t + 1) - dot + 0.5*sq_s   (hn = -h_t)
        v2f accA = pk_fma_vs(hn[0], cr[0], cinit);
        v2f accB = pk_mul_vs(hn[1], cr[1]);
        #pragma unroll
        for (int q = 2; q < 16; q += 2) {
            accA = pk_fma_vs(hn[q],     cr[q],     accA);
            accB = pk_fma_vs(hn[q + 1], cr[q + 1], accB);
        }
        v2f accS = pk_add_vv(accA, accB);
        float keyf = ((accS[0] + accS[1]) + chs) * 1048576.0f;   // * 2^20

        unsigned ki = (unsigned)keyf;           // trunc, monotone (keyf > 0)
        ki = umn(ki, 0x1FFFFFFu);               // clamp: only non-top-10 keys
        unsigned packed = (ki << 7) | (unsigned)i;
        packed = (i == self_i) ? 0xFFFFFFFFu : packed;   // exclude self

        // sorted (ascending) top-10 insert: min/max network, no compares
        bd[9] = umn(bd[9], umx(bd[8], packed));
        bd[8] = umn(bd[8], umx(bd[7], packed));
        bd[7] = umn(bd[7], umx(bd[6], packed));
        bd[6] = umn(bd[6], umx(bd[5], packed));
        bd[5] = umn(bd[5], umx(bd[4], packed));
        bd[4] = umn(bd[4], umx(bd[3], packed));
        bd[3] = umn(bd[3], umx(bd[2], packed));
        bd[2] = umn(bd[2], umx(bd[1], packed));
        bd[1] = umn(bd[1], umx(bd[0], packed));
        bd[0] = umn(bd[0], packed);

        #pragma unroll
        for (int q = 0; q < 16; ++q) cr[q] = nr[q];
        chs = nhs;
    }

    #pragma unroll
    for (int j = 0; j < KNN; ++j) s_key[wid][lane][j] = bd[j];
    __syncthreads();

    float* a_pool = (float*)&s_key[0][0][0];    // [64][33] alias, 8448 B

    if (wid == 0) {
        // 8-way merge of sorted 10-lists; strict < + ascending chunk scan
        // keeps the lowest absolute index on ties (matches top_k stability).
        unsigned k0 = s_key[0][lane][0], k1 = s_key[1][lane][0];
        unsigned k2 = s_key[2][lane][0], k3 = s_key[3][lane][0];
        unsigned k4 = s_key[4][lane][0], k5 = s_key[5][lane][0];
        unsigned k6 = s_key[6][lane][0], k7 = s_key[7][lane][0];
        int p0=0,p1=0,p2=0,p3=0,p4=0,p5=0,p6=0,p7=0;
        int idxs[KNN];
        #pragma unroll
        for (int j = 0; j < KNN; ++j) {
            unsigned mn = k0; int c = 0;
            if (k1 < mn) { mn = k1; c = 1; }
            if (k2 < mn) { mn = k2; c = 2; }
            if (k3 < mn) { mn = k3; c = 3; }
            if (k4 < mn) { mn = k4; c = 4; }
            if (k5 < mn) { mn = k5; c = 5; }
            if (k6 < mn) { mn = k6; c = 6; }
            if (k7 < mn) { mn = k7; c = 7; }
            idxs[j] = (int)(mn & 127u) + (c << 7);
            if      (c == 0) { ++p0; k0 = (p0 < KNN) ? s_key[0][lane][p0] : 0xFFFFFFFFu; }
            else if (c == 1) { ++p1; k1 = (p1 < KNN) ? s_key[1][lane][p1] : 0xFFFFFFFFu; }
            else if (c == 2) { ++p2; k2 = (p2 < KNN) ? s_key[2][lane][p2] : 0xFFFFFFFFu; }
            else if (c == 3) { ++p3; k3 = (p3 < KNN) ? s_key[3][lane][p3] : 0xFFFFFFFFu; }
            else if (c == 4) { ++p4; k4 = (p4 < KNN) ? s_key[4][lane][p4] : 0xFFFFFFFFu; }
            else if (c == 5) { ++p5; k5 = (p5 < KNN) ? s_key[5][lane][p5] : 0xFFFFFFFFu; }
            else if (c == 6) { ++p6; k6 = (p6 < KNN) ? s_key[6][lane][p6] : 0xFFFFFFFFu; }
            else             { ++p7; k7 = (p7 < KNN) ? s_key[7][lane][p7] : 0xFFFFFFFFu; }
        }

        // exact weights + smooth (fp32 recompute, matches reference path)
        float sm[HH];
        #pragma unroll
        for (int j = 0; j < HH; ++j) sm[j] = 0.f;
        float wsum = 0.f;
        #pragma unroll 2
        for (int k = 0; k < KNN; ++k) {
            const v4f* np_ = (const v4f*)(hb + (size_t)idxs[k] * HH);
            float nb[HH];
            #pragma unroll
            for (int q = 0; q < HH / 4; ++q) {
                v4f v = np_[q];
                nb[q*4+0] = v[0]; nb[q*4+1] = v[1]; nb[q*4+2] = v[2]; nb[q*4+3] = v[3];
            }
            float d2 = 0.f;
            #pragma unroll
            for (int q = 0; q < 16; ++q) {
                float df0 = nb[2*q]   + hn[q][0];   // nb - h_t
                float df1 = nb[2*q+1] + hn[q][1];
                d2 = fmaf(df0, df0, d2);
                d2 = fmaf(df1, df1, d2);
            }
            float wk = expf(-0.5f * d2);
            wsum += wk;
            #pragma unroll
            for (int j = 0; j < HH; ++j) sm[j] = fmaf(wk, nb[j], sm[j]);
        }
        float inv = 1.0f / (wsum + 1e-8f);
        #pragma unroll
        for (int j = 0; j < HH; ++j) {
            float lap = -fmaf(sm[j], inv, hn[j >> 1][j & 1]);  // h_t - smooth
            a_pool[lane * 33 + j] = tanhf(lap);
        }
    }
    __syncthreads();

    // out = a @ W2 + b2 ; 512 threads -> (row r, 4 consecutive output dims)
    int r   = tid >> 3;
    int c0_ = (tid & 7) << 2;
    float o[4];
    #pragma unroll
    for (int u = 0; u < 4; ++u) o[u] = b2s[c0_ + u];
    #pragma unroll
    for (int j = 0; j < HH; ++j) {
        float av = a_pool[r * 33 + j];
        #pragma unroll
        for (int u = 0; u < 4; ++u) o[u] = fmaf(av, w2s[j][c0_ + u], o[u]);
    }
    float* op = out + ((size_t)bb * TT + rb + r) * HH + c0_;
    float4 o1 = { o[0], o[1], o[2], o[3] };
    *((float4*)op) = o1;
}

extern "C" void kernel_launch(void* const* d_in, const int* in_sizes, int n_in,
                              void* d_out, int out_size, void* d_ws, size_t ws_size,
                              hipStream_t stream) {
    const float* x  = (const float*)d_in[0];
    const float* W1 = (const float*)d_in[1];
    const float* b1 = (const float*)d_in[2];
    const float* W2 = (const float*)d_in[3];
    const float* b2 = (const float*)d_in[4];
    float* outp = (float*)d_out;

    float* h   = (float*)d_ws;
    float* hsq = h + (size_t)BB * TT * HH;

    h_kernel<<<(BB * TT) / 256, 256, 0, stream>>>(x, W1, b1, h, hsq);
    lap_kernel<<<BB * (TT / 64), 512, 0, stream>>>(h, hsq, W2, b2, outp);
}

// Round 10
// 162.130 us; speedup vs baseline: 2.0892x; 1.0064x over previous
//
#include <hip/hip_runtime.h>
#include <math.h>

#define BB 64
#define TT 1024
#define CC 64
#define HH 32
#define KNN 10
#define SPLIT 8
#define CHUNK (TT / SPLIT)   // 128

typedef float v2f __attribute__((ext_vector_type(2)));
typedef float v4f __attribute__((ext_vector_type(4)));

__device__ __forceinline__ v2f pk_fma_vs(v2f a_v, v2f b_s, v2f c_v) {
    v2f d;
    asm("v_pk_fma_f32 %0, %1, %2, %3" : "=v"(d) : "v"(a_v), "s"(b_s), "v"(c_v));
    return d;
}
__device__ __forceinline__ v2f pk_mul_vs(v2f a_v, v2f b_s) {
    v2f d;
    asm("v_pk_mul_f32 %0, %1, %2" : "=v"(d) : "v"(a_v), "s"(b_s));
    return d;
}
__device__ __forceinline__ v2f pk_add_vv(v2f a, v2f b) {
    v2f d;
    asm("v_pk_add_f32 %0, %1, %2" : "=v"(d) : "v"(a), "v"(b));
    return d;
}
__device__ __forceinline__ unsigned umn(unsigned a, unsigned b) { return a < b ? a : b; }
__device__ __forceinline__ unsigned umx(unsigned a, unsigned b) { return a > b ? a : b; }

// ---------------- Kernel A: h = x@W1 + b1, hsq[row] = 0.5*|h|^2 * 2^20 -------
__global__ __launch_bounds__(256) void h_kernel(
    const float* __restrict__ x, const float* __restrict__ W1,
    const float* __restrict__ b1, float* __restrict__ h, float* __restrict__ hsq)
{
    __shared__ float w1s[CC][HH];
    __shared__ float b1s[HH];
    int tid = threadIdx.x;
    for (int i = tid; i < CC * HH; i += 256) w1s[i >> 5][i & 31] = W1[i];
    if (tid < HH) b1s[tid] = b1[tid];
    __syncthreads();

    int row = blockIdx.x * 256 + tid;
    const float4* xr = (const float4*)(x + (size_t)row * CC);
    float acc[HH];
    #pragma unroll
    for (int j = 0; j < HH; ++j) acc[j] = b1s[j];
    #pragma unroll
    for (int c4 = 0; c4 < CC / 4; ++c4) {
        float4 xv = xr[c4];
        #pragma unroll
        for (int j = 0; j < HH; ++j) {
            acc[j] = fmaf(xv.x, w1s[c4 * 4 + 0][j], acc[j]);
            acc[j] = fmaf(xv.y, w1s[c4 * 4 + 1][j], acc[j]);
            acc[j] = fmaf(xv.z, w1s[c4 * 4 + 2][j], acc[j]);
            acc[j] = fmaf(xv.w, w1s[c4 * 4 + 3][j], acc[j]);
        }
    }
    float s = 0.f;
    #pragma unroll
    for (int j = 0; j < HH; ++j) s = fmaf(acc[j], acc[j], s);
    float* hr = h + (size_t)row * HH;
    #pragma unroll
    for (int q = 0; q < HH / 4; ++q) {
        float4 v = { acc[4*q], acc[4*q+1], acc[4*q+2], acc[4*q+3] };
        ((float4*)hr)[q] = v;
    }
    hsq[row] = 0.5f * s * 1048576.0f;      // pre-scaled by 2^20 for key fma
}

__device__ __forceinline__ unsigned make_key(const v2f* cr, float chs20,
                                             v2f cinit, const v2f* hn,
                                             int i, int self_i) {
    v2f accA = pk_fma_vs(hn[0], cr[0], cinit);
    v2f accB = pk_mul_vs(hn[1], cr[1]);
    #pragma unroll
    for (int q = 2; q < 16; q += 2) {
        accA = pk_fma_vs(hn[q],     cr[q],     accA);
        accB = pk_fma_vs(hn[q + 1], cr[q + 1], accB);
    }
    v2f s2 = pk_add_vv(accA, accB);
    float sum  = s2[0] + s2[1];                       // (0.5 sq_t + 1) - dot
    float keyf = fmaf(sum, 1048576.0f, chs20);        // *2^20 + 0.5 sq_s*2^20
    unsigned ki = (unsigned)keyf;                     // trunc, monotone (>0)
    ki = umn(ki, 0x1FFFFFFu);                         // clamp: never top-10
    unsigned packed = (ki << 7) | (unsigned)i;
    return (i == self_i) ? 0xFFFFFFFFu : packed;
}

// ------------- Kernel B: kNN + laplace smooth + tanh + W2 GEMM ---------------
// 512 thr = 8 waves; block owns 64 rows (1/lane); wave w scans candidates
// [w*128, w*128+128) (wave-uniform -> s_load/SGPR). Ping-pong row buffers
// (no SGPR copies -> scalar pipe relief). Pair min/max-network insert.
// Epilogue: wk reconstructed from kept keys; gather/smooth parallel over
// all 512 threads (row x 4-dim tiles).
__global__ __launch_bounds__(512, 4) void lap_kernel(
    const float* __restrict__ h, const float* __restrict__ hsq,
    const float* __restrict__ W2, const float* __restrict__ b2,
    float* __restrict__ out)
{
    __shared__ unsigned s_key[SPLIT][64][KNN];   // 20.5 KB (a_pool aliases)
    __shared__ float e_wk[64][KNN];              // 2.5 KB
    __shared__ short e_id[64][KNN];              // 1.25 KB
    __shared__ float e_inv[64];                  // 256 B
    __shared__ float w2s[HH][HH];                // 4 KB
    __shared__ float b2s[HH];

    int tid  = threadIdx.x;
    int lane = tid & 63;
    int wid  = __builtin_amdgcn_readfirstlane(tid >> 6);   // chunk id 0..7

    int bb  = blockIdx.x >> 4;           // batch
    int rb  = (blockIdx.x & 15) << 6;    // row base within batch
    int row = rb + lane;

    for (int i = tid; i < HH * HH; i += 512) w2s[i >> 5][i & 31] = W2[i];
    if (tid < HH) b2s[tid] = b2[tid];

    const float* hb  = h   + (size_t)bb * TT * HH;
    const float* sqb = hsq + (size_t)bb * TT;

    // own row, negated (16 x float2, VGPRs)
    v2f hn[16];
    {
        const v4f* hrp = (const v4f*)(hb + (size_t)row * HH);
        #pragma unroll
        for (int q = 0; q < 8; ++q) {
            v4f v = hrp[q];
            hn[2*q]   = (v2f){ -v[0], -v[1] };
            hn[2*q+1] = (v2f){ -v[2], -v[3] };
        }
    }
    // per-lane bias: 0.5*sq_t + 1 (unscale the 2^20-scaled array)
    v2f cinit = (v2f){ fmaf(sqb[row], 9.5367431640625e-07f, 1.0f), 0.0f };

    int s0 = wid * CHUNK;
    int self_i = row - s0;                      // chunk-local self position
    if ((unsigned)self_i >= (unsigned)CHUNK) self_i = -1;

    unsigned bd0 = 0xFFFFFFFFu, bd1 = 0xFFFFFFFFu, bd2 = 0xFFFFFFFFu,
             bd3 = 0xFFFFFFFFu, bd4 = 0xFFFFFFFFu, bd5 = 0xFFFFFFFFu,
             bd6 = 0xFFFFFFFFu, bd7 = 0xFFFFFFFFu, bd8 = 0xFFFFFFFFu,
             bd9 = 0xFFFFFFFFu;

    // ping-pong buffers (SGPR via "s"-constrained consumers; no copies)
    v2f bufA[16], bufB[16]; float chsA, chsB;
    {
        const v2f* pA = (const v2f*)(hb + (size_t)s0 * HH);
        const v2f* pB = (const v2f*)(hb + (size_t)(s0 + 1) * HH);
        #pragma unroll
        for (int q = 0; q < 16; ++q) { bufA[q] = pA[q]; bufB[q] = pB[q]; }
        chsA = sqb[s0]; chsB = sqb[s0 + 1];
    }

    for (int i = 0; i < CHUNK; i += 2) {
        unsigned kE = make_key(bufA, chsA, cinit, hn, i,     self_i);
        unsigned kO = make_key(bufB, chsB, cinit, hn, i + 1, self_i);

        // issue next pair (tail clamps to 127: harmless reload, never used)
        int i2 = (i + 2 < CHUNK) ? i + 2 : CHUNK - 1;
        int i3 = (i + 3 < CHUNK) ? i + 3 : CHUNK - 1;
        {
            const v2f* pA = (const v2f*)(hb + (size_t)(s0 + i2) * HH);
            const v2f* pB = (const v2f*)(hb + (size_t)(s0 + i3) * HH);
            #pragma unroll
            for (int q = 0; q < 16; ++q) { bufA[q] = pA[q]; bufB[q] = pB[q]; }
            chsA = sqb[s0 + i2]; chsB = sqb[s0 + i3];
        }

        // merged sorted-pair insert into ascending top-10 (min3/max fusable)
        unsigned lo = umn(kE, kO), hi = umx(kE, kO);
        bd9 = umn(umn(bd9, umx(bd8, lo)), umx(bd7, hi));
        bd8 = umn(umn(bd8, umx(bd7, lo)), umx(bd6, hi));
        bd7 = umn(umn(bd7, umx(bd6, lo)), umx(bd5, hi));
        bd6 = umn(umn(bd6, umx(bd5, lo)), umx(bd4, hi));
        bd5 = umn(umn(bd5, umx(bd4, lo)), umx(bd3, hi));
        bd4 = umn(umn(bd4, umx(bd3, lo)), umx(bd2, hi));
        bd3 = umn(umn(bd3, umx(bd2, lo)), umx(bd1, hi));
        bd2 = umn(umn(bd2, umx(bd1, lo)), umx(bd0, hi));
        bd1 = umn(umn(bd1, umx(bd0, lo)), hi);
        bd0 = umn(bd0, lo);
    }

    s_key[wid][lane][0] = bd0; s_key[wid][lane][1] = bd1;
    s_key[wid][lane][2] = bd2; s_key[wid][lane][3] = bd3;
    s_key[wid][lane][4] = bd4; s_key[wid][lane][5] = bd5;
    s_key[wid][lane][6] = bd6; s_key[wid][lane][7] = bd7;
    s_key[wid][lane][8] = bd8; s_key[wid][lane][9] = bd9;
    __syncthreads();

    if (wid == 0) {
        // 8-way merge of sorted 10-lists (strict < keeps lowest chunk on tie)
        unsigned k0 = s_key[0][lane][0], k1 = s_key[1][lane][0];
        unsigned k2 = s_key[2][lane][0], k3 = s_key[3][lane][0];
        unsigned k4 = s_key[4][lane][0], k5 = s_key[5][lane][0];
        unsigned k6 = s_key[6][lane][0], k7 = s_key[7][lane][0];
        int p0=0,p1=0,p2=0,p3=0,p4=0,p5=0,p6=0,p7=0;
        float wsum = 0.f;
        #pragma unroll
        for (int j = 0; j < KNN; ++j) {
            unsigned mn = k0; int c = 0;
            if (k1 < mn) { mn = k1; c = 1; }
            if (k2 < mn) { mn = k2; c = 2; }
            if (k3 < mn) { mn = k3; c = 3; }
            if (k4 < mn) { mn = k4; c = 4; }
            if (k5 < mn) { mn = k5; c = 5; }
            if (k6 < mn) { mn = k6; c = 6; }
            if (k7 < mn) { mn = k7; c = 7; }
            // weight from the kept key: key = (0.5*d2 + 1)*2^20
            float kf = (float)(mn >> 7) * 9.5367431640625e-07f;
            float wk = expf(1.0f - kf);               // exp(-0.5*d2)
            wsum += wk;
            e_id[lane][j] = (short)((int)(mn & 127u) + (c << 7));
            e_wk[lane][j] = wk;
            if      (c == 0) { ++p0; k0 = (p0 < KNN) ? s_key[0][lane][p0] : 0xFFFFFFFFu; }
            else if (c == 1) { ++p1; k1 = (p1 < KNN) ? s_key[1][lane][p1] : 0xFFFFFFFFu; }
            else if (c == 2) { ++p2; k2 = (p2 < KNN) ? s_key[2][lane][p2] : 0xFFFFFFFFu; }
            else if (c == 3) { ++p3; k3 = (p3 < KNN) ? s_key[3][lane][p3] : 0xFFFFFFFFu; }
            else if (c == 4) { ++p4; k4 = (p4 < KNN) ? s_key[4][lane][p4] : 0xFFFFFFFFu; }
            else if (c == 5) { ++p5; k5 = (p5 < KNN) ? s_key[5][lane][p5] : 0xFFFFFFFFu; }
            else if (c == 6) { ++p6; k6 = (p6 < KNN) ? s_key[6][lane][p6] : 0xFFFFFFFFu; }
            else             { ++p7; k7 = (p7 < KNN) ? s_key[7][lane][p7] : 0xFFFFFFFFu; }
        }
        e_inv[lane] = 1.0f / (wsum + 1e-8f);
    }
    __syncthreads();

    // gather + smooth + tanh, parallel over (row, 4-dim group); a_pool
    // aliases s_key (dead after merge). Stride 36 -> 16B-aligned rows.
    float* a_pool = (float*)&s_key[0][0][0];
    {
        int r = tid >> 3;              // 0..63
        int g = (tid & 7) << 2;        // dim base 0,4,...,28
        float ax = 0.f, ay = 0.f, az = 0.f, aw = 0.f;
        #pragma unroll
        for (int k = 0; k < KNN; ++k) {
            int idx  = e_id[r][k];
            float wk = e_wk[r][k];
            const float4 nv = *(const float4*)(hb + (size_t)idx * HH + g);
            ax = fmaf(wk, nv.x, ax);
            ay = fmaf(wk, nv.y, ay);
            az = fmaf(wk, nv.z, az);
            aw = fmaf(wk, nv.w, aw);
        }
        float inv = e_inv[r];
        const float4 hv = *(const float4*)(hb + (size_t)(rb + r) * HH + g);
        float4 av;
        av.x = tanhf(fmaf(-ax, inv, hv.x));
        av.y = tanhf(fmaf(-ay, inv, hv.y));
        av.z = tanhf(fmaf(-az, inv, hv.z));
        av.w = tanhf(fmaf(-aw, inv, hv.w));
        *(float4*)&a_pool[r * 36 + g] = av;
    }
    __syncthreads();

    // out = a @ W2 + b2 ; thread -> (row r, 4 consecutive output dims)
    int r   = tid >> 3;
    int c0_ = (tid & 7) << 2;
    float o[4];
    #pragma unroll
    for (int u = 0; u < 4; ++u) o[u] = b2s[c0_ + u];
    #pragma unroll
    for (int j = 0; j < HH; ++j) {
        float av = a_pool[r * 36 + j];
        #pragma unroll
        for (int u = 0; u < 4; ++u) o[u] = fmaf(av, w2s[j][c0_ + u], o[u]);
    }
    float* op = out + ((size_t)bb * TT + rb + r) * HH + c0_;
    float4 o1 = { o[0], o[1], o[2], o[3] };
    *((float4*)op) = o1;
}

extern "C" void kernel_launch(void* const* d_in, const int* in_sizes, int n_in,
                              void* d_out, int out_size, void* d_ws, size_t ws_size,
                              hipStream_t stream) {
    const float* x  = (const float*)d_in[0];
    const float* W1 = (const float*)d_in[1];
    const float* b1 = (const float*)d_in[2];
    const float* W2 = (const float*)d_in[3];
    const float* b2 = (const float*)d_in[4];
    float* outp = (float*)d_out;

    float* h   = (float*)d_ws;
    float* hsq = h + (size_t)BB * TT * HH;

    h_kernel<<<(BB * TT) / 256, 256, 0, stream>>>(x, W1, b1, h, hsq);
    lap_kernel<<<BB * (TT / 64), 512, 0, stream>>>(h, hsq, W2, b2, outp);
}

// Round 12
// 126.888 us; speedup vs baseline: 2.6695x; 1.2777x over previous
//
#include <hip/hip_runtime.h>
#include <math.h>

#define BB 64
#define TT 1024
#define CC 64
#define HH 32
#define KNN 10
#define SPLIT 8
#define CHUNK (TT / SPLIT)   // 128

typedef float v2f __attribute__((ext_vector_type(2)));
typedef float v4f __attribute__((ext_vector_type(4)));

__device__ __forceinline__ v2f pk_fma_vs(v2f a_v, v2f b_s, v2f c_v) {
    v2f d;
    asm("v_pk_fma_f32 %0, %1, %2, %3" : "=v"(d) : "v"(a_v), "s"(b_s), "v"(c_v));
    return d;
}
__device__ __forceinline__ v2f pk_mul_vs(v2f a_v, v2f b_s) {
    v2f d;
    asm("v_pk_mul_f32 %0, %1, %2" : "=v"(d) : "v"(a_v), "s"(b_s));
    return d;
}
__device__ __forceinline__ v2f pk_add_vv(v2f a, v2f b) {
    v2f d;
    asm("v_pk_add_f32 %0, %1, %2" : "=v"(d) : "v"(a), "v"(b));
    return d;
}
__device__ __forceinline__ unsigned umn(unsigned a, unsigned b) { return a < b ? a : b; }
__device__ __forceinline__ unsigned umx(unsigned a, unsigned b) { return a > b ? a : b; }

// ---------------- Kernel A: h = x@W1 + b1, hsq[row] = 0.5*|h|^2 * 2^20 -------
__global__ __launch_bounds__(256) void h_kernel(
    const float* __restrict__ x, const float* __restrict__ W1,
    const float* __restrict__ b1, float* __restrict__ h, float* __restrict__ hsq)
{
    __shared__ float w1s[CC][HH];
    __shared__ float b1s[HH];
    int tid = threadIdx.x;
    for (int i = tid; i < CC * HH; i += 256) w1s[i >> 5][i & 31] = W1[i];
    if (tid < HH) b1s[tid] = b1[tid];
    __syncthreads();

    int row = blockIdx.x * 256 + tid;
    const float4* xr = (const float4*)(x + (size_t)row * CC);
    float acc[HH];
    #pragma unroll
    for (int j = 0; j < HH; ++j) acc[j] = b1s[j];
    #pragma unroll
    for (int c4 = 0; c4 < CC / 4; ++c4) {
        float4 xv = xr[c4];
        #pragma unroll
        for (int j = 0; j < HH; ++j) {
            acc[j] = fmaf(xv.x, w1s[c4 * 4 + 0][j], acc[j]);
            acc[j] = fmaf(xv.y, w1s[c4 * 4 + 1][j], acc[j]);
            acc[j] = fmaf(xv.z, w1s[c4 * 4 + 2][j], acc[j]);
            acc[j] = fmaf(xv.w, w1s[c4 * 4 + 3][j], acc[j]);
        }
    }
    float s = 0.f;
    #pragma unroll
    for (int j = 0; j < HH; ++j) s = fmaf(acc[j], acc[j], s);
    float* hr = h + (size_t)row * HH;
    #pragma unroll
    for (int q = 0; q < HH / 4; ++q) {
        float4 v = { acc[4*q], acc[4*q+1], acc[4*q+2], acc[4*q+3] };
        ((float4*)hr)[q] = v;
    }
    hsq[row] = 0.5f * s * 1048576.0f;      // pre-scaled by 2^20 for key fma
}

__device__ __forceinline__ unsigned make_key(const v2f* cr, float chs20,
                                             v2f cinit, const v2f* hn,
                                             int i, int self_i) {
    v2f accA = pk_fma_vs(hn[0], cr[0], cinit);
    v2f accB = pk_mul_vs(hn[1], cr[1]);
    #pragma unroll
    for (int q = 2; q < 16; q += 2) {
        accA = pk_fma_vs(hn[q],     cr[q],     accA);
        accB = pk_fma_vs(hn[q + 1], cr[q + 1], accB);
    }
    v2f s2 = pk_add_vv(accA, accB);
    float sum  = s2[0] + s2[1];                       // (0.5 sq_t + 1) - dot
    float keyf = fmaf(sum, 1048576.0f, chs20);        // *2^20 + 0.5 sq_s*2^20
    unsigned ki = (unsigned)keyf;                     // trunc, monotone (>0)
    ki = umn(ki, 0x1FFFFFFu);                         // clamp: never top-10
    unsigned packed = (ki << 7) | (unsigned)i;
    return (i == self_i) ? 0xFFFFFFFFu : packed;
}

// ------------- Kernel B: kNN + laplace smooth + tanh + W2 GEMM ---------------
// 512 thr = 8 waves; block owns 64 rows (1/lane); wave w scans candidates
// [w*128, w*128+128) (wave-uniform -> s_load/SGPR). Ping-pong row buffers.
// XCD-aware batch-grouped swizzle: XCD (g&7) only touches batches
// [8*xcd, 8*xcd+8) -> concurrent working set 1 MB << 4 MB L2 per XCD
// (was: all batches spread across XCDs -> 8.4 MB > L2 -> HBM-latency stalls).
__global__ __launch_bounds__(512, 4) void lap_kernel(
    const float* __restrict__ h, const float* __restrict__ hsq,
    const float* __restrict__ W2, const float* __restrict__ b2,
    float* __restrict__ out)
{
    __shared__ unsigned s_key[SPLIT][64][KNN];   // 20.5 KB (a_pool aliases)
    __shared__ float e_wk[64][KNN];              // 2.5 KB
    __shared__ short e_id[64][KNN];              // 1.25 KB
    __shared__ float e_inv[64];                  // 256 B
    __shared__ float w2s[HH][HH];                // 4 KB
    __shared__ float b2s[HH];

    int tid  = threadIdx.x;
    int lane = tid & 63;
    int wid  = __builtin_amdgcn_readfirstlane(tid >> 6);   // chunk id 0..7

    // bijective XCD/batch swizzle: g -> (xcd, l); batch from (xcd, l&7)
    int g   = blockIdx.x;
    int l   = g >> 3;
    int bb  = ((g & 7) << 3) | (l & 7);   // batch
    int rb  = (l >> 3) << 6;              // row base within batch
    int row = rb + lane;

    for (int i = tid; i < HH * HH; i += 512) w2s[i >> 5][i & 31] = W2[i];
    if (tid < HH) b2s[tid] = b2[tid];

    const float* hb  = h   + (size_t)bb * TT * HH;
    const float* sqb = hsq + (size_t)bb * TT;

    // own row, negated (16 x float2, VGPRs)
    v2f hn[16];
    {
        const v4f* hrp = (const v4f*)(hb + (size_t)row * HH);
        #pragma unroll
        for (int q = 0; q < 8; ++q) {
            v4f v = hrp[q];
            hn[2*q]   = (v2f){ -v[0], -v[1] };
            hn[2*q+1] = (v2f){ -v[2], -v[3] };
        }
    }
    // per-lane bias: 0.5*sq_t + 1 (unscale the 2^20-scaled array)
    v2f cinit = (v2f){ fmaf(sqb[row], 9.5367431640625e-07f, 1.0f), 0.0f };

    int s0 = wid * CHUNK;
    int self_i = row - s0;                      // chunk-local self position
    if ((unsigned)self_i >= (unsigned)CHUNK) self_i = -1;

    unsigned bd0 = 0xFFFFFFFFu, bd1 = 0xFFFFFFFFu, bd2 = 0xFFFFFFFFu,
             bd3 = 0xFFFFFFFFu, bd4 = 0xFFFFFFFFu, bd5 = 0xFFFFFFFFu,
             bd6 = 0xFFFFFFFFu, bd7 = 0xFFFFFFFFu, bd8 = 0xFFFFFFFFu,
             bd9 = 0xFFFFFFFFu;

    // ping-pong buffers (SGPR via "s"-constrained consumers; no copies)
    v2f bufA[16], bufB[16]; float chsA, chsB;
    {
        const v2f* pA = (const v2f*)(hb + (size_t)s0 * HH);
        const v2f* pB = (const v2f*)(hb + (size_t)(s0 + 1) * HH);
        #pragma unroll
        for (int q = 0; q < 16; ++q) { bufA[q] = pA[q]; bufB[q] = pB[q]; }
        chsA = sqb[s0]; chsB = sqb[s0 + 1];
    }

    for (int i = 0; i < CHUNK; i += 2) {
        unsigned kE = make_key(bufA, chsA, cinit, hn, i,     self_i);
        unsigned kO = make_key(bufB, chsB, cinit, hn, i + 1, self_i);

        // issue next pair (tail clamps to 127: harmless reload, never used)
        int i2 = (i + 2 < CHUNK) ? i + 2 : CHUNK - 1;
        int i3 = (i + 3 < CHUNK) ? i + 3 : CHUNK - 1;
        {
            const v2f* pA = (const v2f*)(hb + (size_t)(s0 + i2) * HH);
            const v2f* pB = (const v2f*)(hb + (size_t)(s0 + i3) * HH);
            #pragma unroll
            for (int q = 0; q < 16; ++q) { bufA[q] = pA[q]; bufB[q] = pB[q]; }
            chsA = sqb[s0 + i2]; chsB = sqb[s0 + i3];
        }

        // merged sorted-pair insert into ascending top-10 (min3/max fusable)
        unsigned lo = umn(kE, kO), hi = umx(kE, kO);
        bd9 = umn(umn(bd9, umx(bd8, lo)), umx(bd7, hi));
        bd8 = umn(umn(bd8, umx(bd7, lo)), umx(bd6, hi));
        bd7 = umn(umn(bd7, umx(bd6, lo)), umx(bd5, hi));
        bd6 = umn(umn(bd6, umx(bd5, lo)), umx(bd4, hi));
        bd5 = umn(umn(bd5, umx(bd4, lo)), umx(bd3, hi));
        bd4 = umn(umn(bd4, umx(bd3, lo)), umx(bd2, hi));
        bd3 = umn(umn(bd3, umx(bd2, lo)), umx(bd1, hi));
        bd2 = umn(umn(bd2, umx(bd1, lo)), umx(bd0, hi));
        bd1 = umn(umn(bd1, umx(bd0, lo)), hi);
        bd0 = umn(bd0, lo);
    }

    s_key[wid][lane][0] = bd0; s_key[wid][lane][1] = bd1;
    s_key[wid][lane][2] = bd2; s_key[wid][lane][3] = bd3;
    s_key[wid][lane][4] = bd4; s_key[wid][lane][5] = bd5;
    s_key[wid][lane][6] = bd6; s_key[wid][lane][7] = bd7;
    s_key[wid][lane][8] = bd8; s_key[wid][lane][9] = bd9;
    __syncthreads();

    if (wid == 0) {
        // 8-way merge of sorted 10-lists (strict < keeps lowest chunk on tie)
        unsigned k0 = s_key[0][lane][0], k1 = s_key[1][lane][0];
        unsigned k2 = s_key[2][lane][0], k3 = s_key[3][lane][0];
        unsigned k4 = s_key[4][lane][0], k5 = s_key[5][lane][0];
        unsigned k6 = s_key[6][lane][0], k7 = s_key[7][lane][0];
        int p0=0,p1=0,p2=0,p3=0,p4=0,p5=0,p6=0,p7=0;
        float wsum = 0.f;
        #pragma unroll
        for (int j = 0; j < KNN; ++j) {
            unsigned mn = k0; int c = 0;
            if (k1 < mn) { mn = k1; c = 1; }
            if (k2 < mn) { mn = k2; c = 2; }
            if (k3 < mn) { mn = k3; c = 3; }
            if (k4 < mn) { mn = k4; c = 4; }
            if (k5 < mn) { mn = k5; c = 5; }
            if (k6 < mn) { mn = k6; c = 6; }
            if (k7 < mn) { mn = k7; c = 7; }
            // weight from the kept key: key = (0.5*d2 + 1)*2^20
            float kf = (float)(mn >> 7) * 9.5367431640625e-07f;
            float wk = expf(1.0f - kf);               // exp(-0.5*d2)
            wsum += wk;
            e_id[lane][j] = (short)((int)(mn & 127u) + (c << 7));
            e_wk[lane][j] = wk;
            if      (c == 0) { ++p0; k0 = (p0 < KNN) ? s_key[0][lane][p0] : 0xFFFFFFFFu; }
            else if (c == 1) { ++p1; k1 = (p1 < KNN) ? s_key[1][lane][p1] : 0xFFFFFFFFu; }
            else if (c == 2) { ++p2; k2 = (p2 < KNN) ? s_key[2][lane][p2] : 0xFFFFFFFFu; }
            else if (c == 3) { ++p3; k3 = (p3 < KNN) ? s_key[3][lane][p3] : 0xFFFFFFFFu; }
            else if (c == 4) { ++p4; k4 = (p4 < KNN) ? s_key[4][lane][p4] : 0xFFFFFFFFu; }
            else if (c == 5) { ++p5; k5 = (p5 < KNN) ? s_key[5][lane][p5] : 0xFFFFFFFFu; }
            else if (c == 6) { ++p6; k6 = (p6 < KNN) ? s_key[6][lane][p6] : 0xFFFFFFFFu; }
            else             { ++p7; k7 = (p7 < KNN) ? s_key[7][lane][p7] : 0xFFFFFFFFu; }
        }
        e_inv[lane] = 1.0f / (wsum + 1e-8f);
    }
    __syncthreads();

    // gather + smooth + tanh, parallel over (row, 4-dim group); a_pool
    // aliases s_key (dead after merge). Stride 36 -> 16B-aligned rows.
    float* a_pool = (float*)&s_key[0][0][0];
    {
        int r = tid >> 3;              // 0..63
        int g2 = (tid & 7) << 2;       // dim base 0,4,...,28
        float ax = 0.f, ay = 0.f, az = 0.f, aw = 0.f;
        #pragma unroll
        for (int k = 0; k < KNN; ++k) {
            int idx  = e_id[r][k];
            float wk = e_wk[r][k];
            const float4 nv = *(const float4*)(hb + (size_t)idx * HH + g2);
            ax = fmaf(wk, nv.x, ax);
            ay = fmaf(wk, nv.y, ay);
            az = fmaf(wk, nv.z, az);
            aw = fmaf(wk, nv.w, aw);
        }
        float inv = e_inv[r];
        const float4 hv = *(const float4*)(hb + (size_t)(rb + r) * HH + g2);
        float4 av;
        av.x = tanhf(fmaf(-ax, inv, hv.x));
        av.y = tanhf(fmaf(-ay, inv, hv.y));
        av.z = tanhf(fmaf(-az, inv, hv.z));
        av.w = tanhf(fmaf(-aw, inv, hv.w));
        *(float4*)&a_pool[r * 36 + g2] = av;
    }
    __syncthreads();

    // out = a @ W2 + b2 ; thread -> (row r, 4 consecutive output dims)
    int r   = tid >> 3;
    int c0_ = (tid & 7) << 2;
    float o[4];
    #pragma unroll
    for (int u = 0; u < 4; ++u) o[u] = b2s[c0_ + u];
    #pragma unroll
    for (int j = 0; j < HH; ++j) {
        float av = a_pool[r * 36 + j];
        #pragma unroll
        for (int u = 0; u < 4; ++u) o[u] = fmaf(av, w2s[j][c0_ + u], o[u]);
    }
    float* op = out + ((size_t)bb * TT + rb + r) * HH + c0_;
    float4 o1 = { o[0], o[1], o[2], o[3] };
    *((float4*)op) = o1;
}

extern "C" void kernel_launch(void* const* d_in, const int* in_sizes, int n_in,
                              void* d_out, int out_size, void* d_ws, size_t ws_size,
                              hipStream_t stream) {
    const float* x  = (const float*)d_in[0];
    const float* W1 = (const float*)d_in[1];
    const float* b1 = (const float*)d_in[2];
    const float* W2 = (const float*)d_in[3];
    const float* b2 = (const float*)d_in[4];
    float* outp = (float*)d_out;

    float* h   = (float*)d_ws;
    float* hsq = h + (size_t)BB * TT * HH;

    h_kernel<<<(BB * TT) / 256, 256, 0, stream>>>(x, W1, b1, h, hsq);
    lap_kernel<<<BB * (TT / 64), 512, 0, stream>>>(h, hsq, W2, b2, outp);
}